// Round 5
// baseline (196.145 us; speedup 1.0000x reference)
//
#include <hip/hip_runtime.h>
#include <math.h>

// Shapes: B=4096, N=128, D=64, H=256, O=128
// d_out (floats): out[B*128] | mem_new[B*128*64] | h_new[B*256] | c_new[B*256]
// ws: bsum f32[1024] | bh_b f32[256] | bf16: Wg_il[1024][448] (gate-interleaved:
//     p = uc*256+g*64+ul <-> R = g*256+uc*64+ul) | Wr_b[128][256] | Wh_b[256][256] |
//     Wo_b[128][320]

typedef __attribute__((ext_vector_type(8))) short bf16x8;
typedef __attribute__((ext_vector_type(4))) float f32x4;
typedef __attribute__((ext_vector_type(4))) unsigned short us4;

#define MFMA16(a, b, c) __builtin_amdgcn_mfma_f32_16x16x32_bf16(a, b, c, 0, 0, 0)

__device__ __forceinline__ float sigf(float v) { return 1.f / (1.f + __expf(-v)); }

__device__ __forceinline__ unsigned short f2bf(float f) {
    unsigned u = __builtin_bit_cast(unsigned, f);
    u = (u + 0x7FFFu + ((u >> 16) & 1u)) >> 16;
    return (unsigned short)u;
}

// row-major [*][COLS] bf16 LDS tile; 8-col groups permuted by row&3 within 32-col chunks
__device__ __forceinline__ int swaddr(int r, int c, int COLS) {
    return r * COLS + (c & ~31) + ((((c >> 3) & 3) ^ (r & 3)) << 3) + (c & 7);
}

// ---------------- pack: weights -> bf16 (gate-interleaved Wg), biases ----------------
__global__ __launch_bounds__(256) void p_pack(
    const float* __restrict__ Wih, const float* __restrict__ Whh,
    const float* __restrict__ bih, const float* __restrict__ bhh,
    const float* __restrict__ Wr, const float* __restrict__ Ww,
    const float* __restrict__ We, const float* __restrict__ Wa,
    const float* __restrict__ bw, const float* __restrict__ be,
    const float* __restrict__ ba, const float* __restrict__ Wo,
    unsigned short* __restrict__ Wg, unsigned short* __restrict__ Wr_b,
    unsigned short* __restrict__ Wh_b, unsigned short* __restrict__ Wo_b,
    float* __restrict__ bsum, float* __restrict__ bh_b)
{
    int idx = blockIdx.x * 256 + threadIdx.x;
    int stride = gridDim.x * 256;
    for (int i = idx; i < 1024 * 448; i += stride) {
        int p = i / 448, k = i - p * 448;
        int uc = p >> 8, g = (p >> 6) & 3, ul = p & 63;
        int R = g * 256 + uc * 64 + ul;
        float v = (k < 192) ? Wih[(size_t)R * 192 + k] : Whh[(size_t)R * 256 + (k - 192)];
        Wg[i] = f2bf(v);
    }
    for (int i = idx; i < 128 * 256; i += stride) Wr_b[i] = f2bf(Wr[i]);
    for (int i = idx; i < 256 * 256; i += stride) {
        int r = i >> 8, cc = i & 255;
        float v = (r < 128) ? Ww[(size_t)r * 256 + cc]
                : (r < 192) ? We[(size_t)(r - 128) * 256 + cc]
                            : Wa[(size_t)(r - 192) * 256 + cc];
        Wh_b[i] = f2bf(v);
    }
    for (int i = idx; i < 128 * 320; i += stride) Wo_b[i] = f2bf(Wo[i]);
    for (int i = idx; i < 1024; i += stride) bsum[i] = bih[i] + bhh[i];
    for (int i = idx; i < 256; i += stride)
        bh_b[i] = (i < 128) ? bw[i] : (i < 192 ? be[i - 128] : ba[i - 192]);
}

// ---------------- mega: everything else, 8 rows/block ----------------
// grid 512, block 256 (4 waves). B-operands for all GEMMs read directly
// global->VGPR (L2-resident); A-operands in swizzled LDS.
__global__ __launch_bounds__(256) void mega(
    const float* __restrict__ x, const float* __restrict__ h,
    const float* __restrict__ c, const float* __restrict__ mem,
    const unsigned short* __restrict__ Wg, const unsigned short* __restrict__ Wr_b,
    const unsigned short* __restrict__ Wh_b, const unsigned short* __restrict__ Wo_b,
    const float* __restrict__ bsum, const float* __restrict__ bh_b,
    const float* __restrict__ br, const float* __restrict__ bo,
    float* __restrict__ outp, float* __restrict__ mem_new,
    float* __restrict__ h_new, float* __restrict__ c_new)
{
    __shared__ unsigned short Agl[16 * 448];   // [x(128)|rv(64)|h(256)], rows 8..15 unused
    __shared__ unsigned short hA[16 * 320];    // [h_new(256)|rv(64)]
    __shared__ float sc[8][256];
    __shared__ float wL[8][128];
    __shared__ __align__(16) float eL[8][64];
    __shared__ __align__(16) float aL[8][64];

    int t = threadIdx.x;
    int w = t >> 6, lane = t & 63;
    int cl = lane & 15, ks = lane >> 4;
    int b0 = blockIdx.x * 8;

    // ---- phase L: pack x,h for these 8 rows into Agl ----
    {
        int row = t >> 5, q = t & 31;   // row 0..7, q 0..31
        f32x4 v = *(const f32x4*)(x + (size_t)(b0 + row) * 128 + q * 4);
        us4 o = { f2bf(v[0]), f2bf(v[1]), f2bf(v[2]), f2bf(v[3]) };
        *(us4*)(Agl + swaddr(row, q * 4, 448)) = o;

        const f32x4* hp = (const f32x4*)(h + (size_t)(b0 + row) * 256 + q * 8);
        f32x4 v0 = hp[0], v1 = hp[1];
        us4 o0 = { f2bf(v0[0]), f2bf(v0[1]), f2bf(v0[2]), f2bf(v0[3]) };
        us4 o1 = { f2bf(v1[0]), f2bf(v1[1]), f2bf(v1[2]), f2bf(v1[3]) };
        int a0 = swaddr(row, 192 + q * 8, 448);
        *(us4*)(Agl + a0) = o0;
        *(us4*)(Agl + a0 + 4) = o1;
    }
    __syncthreads();   // S1

    // ---- phase 1: scores = h @ Wr^T (8 rows x 128 cols, K=256) ----
    {
        f32x4 acc0 = {0.f, 0.f, 0.f, 0.f}, acc1 = {0.f, 0.f, 0.f, 0.f};
        int col0 = (w * 2 + 0) * 16 + cl, col1 = (w * 2 + 1) * 16 + cl;
        const unsigned short* bp0 = Wr_b + (size_t)col0 * 256 + ks * 8;
        const unsigned short* bp1 = Wr_b + (size_t)col1 * 256 + ks * 8;
#pragma unroll
        for (int kc = 0; kc < 8; ++kc) {
            bf16x8 a = *(const bf16x8*)(Agl + swaddr(cl, 192 + kc * 32 + ks * 8, 448));
            acc0 = MFMA16(a, *(const bf16x8*)(bp0 + kc * 32), acc0);
            acc1 = MFMA16(a, *(const bf16x8*)(bp1 + kc * 32), acc1);
        }
        if (ks < 2) {
#pragma unroll
            for (int r = 0; r < 4; ++r) {
                sc[ks * 4 + r][col0] = acc0[r];
                sc[ks * 4 + r][col1] = acc1[r];
            }
        }
    }
    __syncthreads();   // S2

    // ---- phase 2: read softmax -> wL ----
    if (t < 128) {
        int row = t >> 4, l = t & 15;
        float v[8];
#pragma unroll
        for (int j = 0; j < 8; ++j) v[j] = sc[row][l + 16 * j] + br[l + 16 * j];
        float m = v[0];
#pragma unroll
        for (int j = 1; j < 8; ++j) m = fmaxf(m, v[j]);
#pragma unroll
        for (int mk = 8; mk >= 1; mk >>= 1) m = fmaxf(m, __shfl_xor(m, mk));
        float s = 0.f;
#pragma unroll
        for (int j = 0; j < 8; ++j) { v[j] = __expf(v[j] - m); s += v[j]; }
#pragma unroll
        for (int mk = 8; mk >= 1; mk >>= 1) s += __shfl_xor(s, mk);
        float inv = 1.f / s;
#pragma unroll
        for (int j = 0; j < 8; ++j) wL[row][l + 16 * j] = v[j] * inv;
    }
    __syncthreads();   // S3

    // ---- phase 3: read_vec stream (2 rows per wave) ----
    {
        int dg = cl, ng = ks;
#pragma unroll
        for (int rr = 0; rr < 2; ++rr) {
            int r = w * 2 + rr;
            const f32x4* m4 = (const f32x4*)(mem + (size_t)(b0 + r) * 8192);
            f32x4 acc = {0.f, 0.f, 0.f, 0.f};
#pragma unroll
            for (int j = 0; j < 32; ++j) {
                int n = ng + 4 * j;
                acc += wL[r][n] * m4[n * 16 + dg];
            }
#pragma unroll
            for (int i = 0; i < 4; ++i) {
                acc[i] += __shfl_xor(acc[i], 16);
                acc[i] += __shfl_xor(acc[i], 32);
            }
            if (lane < 16) {
                int d0 = dg * 4;
                us4 o = { f2bf(acc[0]), f2bf(acc[1]), f2bf(acc[2]), f2bf(acc[3]) };
                *(us4*)(Agl + swaddr(r, 128 + d0, 448)) = o;
                *(us4*)(hA + swaddr(r, 256 + d0, 320)) = o;
            }
        }
    }
    __syncthreads();   // S4

    // ---- phase 4: gates GEMM (K=448) + LSTM, gate-interleaved Wg ----
    {
        bf16x8 aF[14];
#pragma unroll
        for (int kc = 0; kc < 14; ++kc)
            aF[kc] = *(const bf16x8*)(Agl + swaddr(cl, kc * 32 + ks * 8, 448));
#pragma unroll 1
        for (int uc = 0; uc < 4; ++uc) {
            f32x4 acc0 = {0.f,0.f,0.f,0.f}, acc1 = {0.f,0.f,0.f,0.f};
            f32x4 acc2 = {0.f,0.f,0.f,0.f}, acc3 = {0.f,0.f,0.f,0.f};
            const unsigned short* bp0 = Wg + (size_t)(uc * 256 +   0 + w * 16 + cl) * 448 + ks * 8;
            const unsigned short* bp1 = Wg + (size_t)(uc * 256 +  64 + w * 16 + cl) * 448 + ks * 8;
            const unsigned short* bp2 = Wg + (size_t)(uc * 256 + 128 + w * 16 + cl) * 448 + ks * 8;
            const unsigned short* bp3 = Wg + (size_t)(uc * 256 + 192 + w * 16 + cl) * 448 + ks * 8;
#pragma unroll
            for (int kc = 0; kc < 14; ++kc) {
                acc0 = MFMA16(aF[kc], *(const bf16x8*)(bp0 + kc * 32), acc0);
                acc1 = MFMA16(aF[kc], *(const bf16x8*)(bp1 + kc * 32), acc1);
                acc2 = MFMA16(aF[kc], *(const bf16x8*)(bp2 + kc * 32), acc2);
                acc3 = MFMA16(aF[kc], *(const bf16x8*)(bp3 + kc * 32), acc3);
            }
            int unit = uc * 64 + w * 16 + cl;
            float bi = bsum[unit], bf_ = bsum[256 + unit];
            float bg = bsum[512 + unit], bo_ = bsum[768 + unit];
            if (ks < 2) {
#pragma unroll
                for (int r = 0; r < 4; ++r) {
                    int lrow = ks * 4 + r, row = b0 + lrow;
                    float iv = sigf(acc0[r] + bi);
                    float fv = sigf(acc1[r] + bf_);
                    float gv = tanhf(acc2[r] + bg);
                    float ov = sigf(acc3[r] + bo_);
                    float cv = fv * c[(size_t)row * 256 + unit] + iv * gv;
                    float hv = ov * tanhf(cv);
                    c_new[(size_t)row * 256 + unit] = cv;
                    h_new[(size_t)row * 256 + unit] = hv;
                    hA[swaddr(lrow, unit, 320)] = f2bf(hv);
                }
            }
        }
    }
    __syncthreads();   // S5

    // ---- phase 5: heads (K=256) + out (K=320) GEMM from hA ----
    {
        f32x4 accH0 = {0.f,0.f,0.f,0.f}, accH1 = {0.f,0.f,0.f,0.f};
        f32x4 accH2 = {0.f,0.f,0.f,0.f}, accH3 = {0.f,0.f,0.f,0.f};
        f32x4 accO0 = {0.f,0.f,0.f,0.f}, accO1 = {0.f,0.f,0.f,0.f};
        const unsigned short* bh0 = Wh_b + (size_t)((w * 4 + 0) * 16 + cl) * 256 + ks * 8;
        const unsigned short* bh1 = Wh_b + (size_t)((w * 4 + 1) * 16 + cl) * 256 + ks * 8;
        const unsigned short* bh2 = Wh_b + (size_t)((w * 4 + 2) * 16 + cl) * 256 + ks * 8;
        const unsigned short* bh3 = Wh_b + (size_t)((w * 4 + 3) * 16 + cl) * 256 + ks * 8;
        const unsigned short* bo0 = Wo_b + (size_t)((w * 2 + 0) * 16 + cl) * 320 + ks * 8;
        const unsigned short* bo1 = Wo_b + (size_t)((w * 2 + 1) * 16 + cl) * 320 + ks * 8;
#pragma unroll
        for (int kc = 0; kc < 10; ++kc) {
            bf16x8 a = *(const bf16x8*)(hA + swaddr(cl, kc * 32 + ks * 8, 320));
            if (kc < 8) {
                accH0 = MFMA16(a, *(const bf16x8*)(bh0 + kc * 32), accH0);
                accH1 = MFMA16(a, *(const bf16x8*)(bh1 + kc * 32), accH1);
                accH2 = MFMA16(a, *(const bf16x8*)(bh2 + kc * 32), accH2);
                accH3 = MFMA16(a, *(const bf16x8*)(bh3 + kc * 32), accH3);
            }
            accO0 = MFMA16(a, *(const bf16x8*)(bo0 + kc * 32), accO0);
            accO1 = MFMA16(a, *(const bf16x8*)(bo1 + kc * 32), accO1);
        }
        if (ks < 2) {
            f32x4 aH[4] = { accH0, accH1, accH2, accH3 };
#pragma unroll
            for (int f = 0; f < 4; ++f) {
                int col = (w * 4 + f) * 16 + cl;
                float bb = bh_b[col];
#pragma unroll
                for (int r = 0; r < 4; ++r) sc[ks * 4 + r][col] = aH[f][r] + bb;
            }
            f32x4 aO[2] = { accO0, accO1 };
#pragma unroll
            for (int f = 0; f < 2; ++f) {
                int col = (w * 2 + f) * 16 + cl;
                float bb = bo[col];
#pragma unroll
                for (int r = 0; r < 4; ++r)
                    outp[(size_t)(b0 + ks * 4 + r) * 128 + col] = aO[f][r] + bb;
            }
        }
    }
    __syncthreads();   // S6

    // ---- phase 6: write softmax + erase/add activations ----
    if (t < 128) {
        int row = t >> 4, l = t & 15;
        float v[8];
#pragma unroll
        for (int j = 0; j < 8; ++j) v[j] = sc[row][l + 16 * j];
        float m = v[0];
#pragma unroll
        for (int j = 1; j < 8; ++j) m = fmaxf(m, v[j]);
#pragma unroll
        for (int mk = 8; mk >= 1; mk >>= 1) m = fmaxf(m, __shfl_xor(m, mk));
        float s = 0.f;
#pragma unroll
        for (int j = 0; j < 8; ++j) { v[j] = __expf(v[j] - m); s += v[j]; }
#pragma unroll
        for (int mk = 8; mk >= 1; mk >>= 1) s += __shfl_xor(s, mk);
        float inv = 1.f / s;
#pragma unroll
        for (int j = 0; j < 8; ++j) wL[row][l + 16 * j] = v[j] * inv;
#pragma unroll
        for (int j = 0; j < 4; ++j) eL[row][l + 16 * j] = sigf(sc[row][128 + l + 16 * j]);
#pragma unroll
        for (int j = 0; j < 4; ++j) aL[row][l + 16 * j] = tanhf(sc[row][192 + l + 16 * j]);
    }
    __syncthreads();   // S7

    // ---- phase 7: mem RMW stream (2 rows per wave), NT stores ----
    {
        int dg = cl, ng = ks;
        f32x4 one = {1.f, 1.f, 1.f, 1.f};
#pragma unroll
        for (int rr = 0; rr < 2; ++rr) {
            int r = w * 2 + rr;
            const f32x4* m4 = (const f32x4*)(mem + (size_t)(b0 + r) * 8192);
            f32x4* o4 = (f32x4*)(mem_new + (size_t)(b0 + r) * 8192);
            f32x4 e4 = *(const f32x4*)&eL[r][dg * 4];
            f32x4 a4 = *(const f32x4*)&aL[r][dg * 4];
#pragma unroll
            for (int j = 0; j < 32; ++j) {
                int n = ng + 4 * j;
                float wv = wL[r][n];
                f32x4 m = m4[n * 16 + dg];
                f32x4 res = m * (one - e4 * wv) + a4 * wv;
                __builtin_nontemporal_store(res, &o4[n * 16 + dg]);
            }
        }
    }
}

extern "C" void kernel_launch(void* const* d_in, const int* in_sizes, int n_in,
                              void* d_out, int out_size, void* d_ws, size_t ws_size,
                              hipStream_t stream)
{
    const float* x    = (const float*)d_in[0];
    const float* mem  = (const float*)d_in[1];
    const float* h    = (const float*)d_in[2];
    const float* c    = (const float*)d_in[3];
    const float* Wih  = (const float*)d_in[4];
    const float* Whh  = (const float*)d_in[5];
    const float* bih  = (const float*)d_in[6];
    const float* bhh  = (const float*)d_in[7];
    const float* Wr   = (const float*)d_in[8];
    const float* br   = (const float*)d_in[9];
    const float* Ww   = (const float*)d_in[10];
    const float* bw   = (const float*)d_in[11];
    const float* We   = (const float*)d_in[12];
    const float* be   = (const float*)d_in[13];
    const float* Wa   = (const float*)d_in[14];
    const float* ba   = (const float*)d_in[15];
    const float* Wo   = (const float*)d_in[16];
    const float* bo   = (const float*)d_in[17];

    float* out     = (float*)d_out;
    float* mem_new = out + 524288;
    float* h_new   = out + 34078720;
    float* c_new   = out + 35127296;

    float* ws   = (float*)d_ws;
    float* bsum = ws;                          // 1024
    float* bh_b = ws + 1024;                   // 256
    unsigned short* ub   = (unsigned short*)(ws + 1280);
    unsigned short* Wg   = ub;                 // 1024*448 = 458752
    unsigned short* Wr_b = ub + 458752;        // 128*256 = 32768
    unsigned short* Wh_b = ub + 491520;        // 256*256 = 65536
    unsigned short* Wo_b = ub + 557056;        // 128*320 = 40960

    p_pack<<<256, 256, 0, stream>>>(Wih, Whh, bih, bhh, Wr, Ww, We, Wa, bw, be, ba, Wo,
                                    Wg, Wr_b, Wh_b, Wo_b, bsum, bh_b);
    mega<<<512, 256, 0, stream>>>(x, h, c, mem, Wg, Wr_b, Wh_b, Wo_b, bsum, bh_b, br, bo,
                                  out, mem_new, h_new, c_new);
}

// Round 6
// 111.848 us; speedup vs baseline: 1.7537x; 1.7537x over previous
//
#include <hip/hip_runtime.h>
#include <math.h>

// Shapes: B=4096, N=128, D=64, H=256, O=128
// d_out (floats): out[B*128] | mem_new[B*128*64] | h_new[B*256] | c_new[B*256]
// ws: read_w f32 | write_w f32 | erase f32 | addv f32 | bsum f32 | bh_b f32 |
//     bf16: Ag[4096][448]=[x|rv|h], Aout[4096][320]=[h_new|rv], Wg[1024][448],
//           Wh_b[256][256], Wo_b[128][320]

typedef __attribute__((ext_vector_type(8))) short bf16x8;
typedef __attribute__((ext_vector_type(4))) float f32x4;
typedef __attribute__((ext_vector_type(4))) unsigned short us4;

#define MFMA16(a, b, c) __builtin_amdgcn_mfma_f32_16x16x32_bf16(a, b, c, 0, 0, 0)
#define GLL16(gp, lp) __builtin_amdgcn_global_load_lds( \
    (const __attribute__((address_space(1))) void*)(gp), \
    (__attribute__((address_space(3))) void*)(lp), 16, 0, 0)
#define SW(row, s) ((s) ^ ((row) & 3))

__device__ __forceinline__ float sigf(float v) { return 1.f / (1.f + __expf(-v)); }

__device__ __forceinline__ unsigned short f2bf(float f) {
    unsigned u = __builtin_bit_cast(unsigned, f);
    u = (u + 0x7FFFu + ((u >> 16) & 1u)) >> 16;
    return (unsigned short)u;
}

// =============== kA: pack + read-attn scores + softmax -> read_w ===============
// grid 256 (16 rows/block), block 256 (4 waves).
__global__ __launch_bounds__(256) void kA_prep(
    const float* __restrict__ Wih, const float* __restrict__ Whh,
    const float* __restrict__ bih, const float* __restrict__ bhh,
    const float* __restrict__ Wr, const float* __restrict__ br,
    const float* __restrict__ Ww, const float* __restrict__ We,
    const float* __restrict__ Wa, const float* __restrict__ bw,
    const float* __restrict__ be, const float* __restrict__ ba,
    const float* __restrict__ Wo, const float* __restrict__ x,
    const float* __restrict__ h,
    unsigned short* __restrict__ Wg, float* __restrict__ bsum,
    unsigned short* __restrict__ Wh_b, float* __restrict__ bh_b,
    unsigned short* __restrict__ Wo_b, unsigned short* __restrict__ Ag,
    float* __restrict__ read_w)
{
    __shared__ unsigned short As[16 * 32];
    __shared__ unsigned short Bs[128 * 32];
    __shared__ float sc[16][128];

    int t = threadIdx.x;
    int wid = t >> 6, lane = t & 63;
    int cl = lane & 15, ks = lane >> 4;
    int b0 = blockIdx.x * 16;

    // ---- phase 0: pack weights + x,h (striped across all blocks) ----
    int idx = blockIdx.x * 256 + t;
    int stride = gridDim.x * 256;
    for (int i = idx; i < 1024 * 448; i += stride) {
        int r = i / 448, cc = i - r * 448;
        float v = (cc < 192) ? Wih[(size_t)r * 192 + cc] : Whh[(size_t)r * 256 + (cc - 192)];
        Wg[i] = f2bf(v);
    }
    for (int i = idx; i < 1024; i += stride) bsum[i] = bih[i] + bhh[i];
    for (int i = idx; i < 256 * 256; i += stride) {
        int r = i >> 8, cc = i & 255;
        float v = (r < 128) ? Ww[(size_t)r * 256 + cc]
                : (r < 192) ? We[(size_t)(r - 128) * 256 + cc]
                            : Wa[(size_t)(r - 192) * 256 + cc];
        Wh_b[i] = f2bf(v);
    }
    for (int i = idx; i < 256; i += stride)
        bh_b[i] = (i < 128) ? bw[i] : (i < 192 ? be[i - 128] : ba[i - 192]);
    for (int i = idx; i < 128 * 320; i += stride) Wo_b[i] = f2bf(Wo[i]);
    for (int i = idx; i < 4096 * 96; i += stride) {
        int row = i / 96, j = i - row * 96;
        float4 v = (j < 32) ? ((const float4*)(x + (size_t)row * 128))[j]
                            : ((const float4*)(h + (size_t)row * 256))[j - 32];
        us4 o = { f2bf(v.x), f2bf(v.y), f2bf(v.z), f2bf(v.w) };
        int col = (j < 32) ? j * 4 : 192 + (j - 32) * 4;
        *(us4*)(Ag + (size_t)row * 448 + col) = o;
    }

    // ---- phase 1: scores = h @ Wr^T  (16 rows x 128 cols, K=256) ----
    int aOff = cl * 32 + SW(cl, ks) * 8;
    int bOff[4];
#pragma unroll
    for (int f = 0; f < 4; ++f) {
        int br_ = (wid * 4 + f) * 16 + cl;
        bOff[f] = br_ * 32 + SW(br_, ks) * 8;
    }
    f32x4 acc[4] = {};
    for (int kc = 0; kc < 8; ++kc) {
        __syncthreads();
        {   // h tile: 16 rows x 32 k -> bf16 LDS (swizzled)
            int row = t >> 4, k0 = (t & 15) * 2;
            float2 hv = *(const float2*)(h + (size_t)(b0 + row) * 256 + kc * 32 + k0);
            unsigned pk = (unsigned)f2bf(hv.x) | ((unsigned)f2bf(hv.y) << 16);
            *(unsigned*)(As + row * 32 + SW(row, k0 >> 3) * 8 + (k0 & 7)) = pk;
        }
        {   // Wr tile: 128 rows x 32 k
            int row = t >> 1, k0 = (t & 1) * 16;
            const float4* wp = (const float4*)(Wr + (size_t)row * 256 + kc * 32 + k0);
            float4 w0 = wp[0], w1 = wp[1], w2 = wp[2], w3 = wp[3];
            us4 p0 = { f2bf(w0.x), f2bf(w0.y), f2bf(w0.z), f2bf(w0.w) };
            us4 p1 = { f2bf(w1.x), f2bf(w1.y), f2bf(w1.z), f2bf(w1.w) };
            us4 p2 = { f2bf(w2.x), f2bf(w2.y), f2bf(w2.z), f2bf(w2.w) };
            us4 p3 = { f2bf(w3.x), f2bf(w3.y), f2bf(w3.z), f2bf(w3.w) };
            int g0 = k0 >> 3;
            unsigned short* basep = Bs + row * 32;
            *(us4*)(basep + SW(row, g0) * 8)     = p0;
            *(us4*)(basep + SW(row, g0) * 8 + 4) = p1;
            *(us4*)(basep + SW(row, g0 + 1) * 8)     = p2;
            *(us4*)(basep + SW(row, g0 + 1) * 8 + 4) = p3;
        }
        __syncthreads();
        if (wid < 2) {
            bf16x8 a = *(const bf16x8*)(As + aOff);
#pragma unroll
            for (int f = 0; f < 4; ++f)
                acc[f] = MFMA16(a, *(const bf16x8*)(Bs + bOff[f]), acc[f]);
        }
    }
    if (wid < 2) {
#pragma unroll
        for (int f = 0; f < 4; ++f)
#pragma unroll
            for (int r = 0; r < 4; ++r)
                sc[ks * 4 + r][(wid * 4 + f) * 16 + cl] = acc[f][r];
    }
    __syncthreads();
    {   // softmax: 16 threads per row -> read_w
        int row = t >> 4, l = t & 15;
        float v[8];
#pragma unroll
        for (int j = 0; j < 8; ++j) v[j] = sc[row][l + 16 * j] + br[l + 16 * j];
        float m = v[0];
#pragma unroll
        for (int j = 1; j < 8; ++j) m = fmaxf(m, v[j]);
#pragma unroll
        for (int mk = 8; mk >= 1; mk >>= 1) m = fmaxf(m, __shfl_xor(m, mk));
        float s = 0.f;
#pragma unroll
        for (int j = 0; j < 8; ++j) { v[j] = __expf(v[j] - m); s += v[j]; }
#pragma unroll
        for (int mk = 8; mk >= 1; mk >>= 1) s += __shfl_xor(s, mk);
        float inv = 1.f / s;
#pragma unroll
        for (int j = 0; j < 8; ++j)
            read_w[(size_t)(b0 + row) * 128 + l + 16 * j] = v[j] * inv;
    }
}

// =============== k2: read_vec stream (grid 4096, full occupancy) ===============
__global__ __launch_bounds__(256) void k2_read_vec(
    const float* __restrict__ mem, const float* __restrict__ read_w,
    unsigned short* __restrict__ Ag, unsigned short* __restrict__ Aout)
{
    __shared__ float part[16][68];
    int t = threadIdx.x;
    int b = blockIdx.x;
    int np = t >> 4, d4 = t & 15;
    const float4* m4 = (const float4*)(mem + (size_t)b * 8192);
    float4 acc = make_float4(0.f, 0.f, 0.f, 0.f);
#pragma unroll
    for (int j = 0; j < 8; ++j) {
        int n = np + 16 * j;
        float w = read_w[(size_t)b * 128 + n];
        float4 mv = m4[t + 256 * j];
        acc.x += w * mv.x; acc.y += w * mv.y; acc.z += w * mv.z; acc.w += w * mv.w;
    }
    part[np][d4 * 4 + 0] = acc.x; part[np][d4 * 4 + 1] = acc.y;
    part[np][d4 * 4 + 2] = acc.z; part[np][d4 * 4 + 3] = acc.w;
    __syncthreads();
    if (t < 64) {
        float s = 0.f;
#pragma unroll
        for (int q = 0; q < 16; ++q) s += part[q][t];
        unsigned short bv = f2bf(s);
        Ag[(size_t)b * 448 + 128 + t] = bv;
        Aout[(size_t)b * 320 + 256 + t] = bv;
    }
}

// =============== kB: gates GEMM [MFMA] + LSTM pointwise ===============
// grid (64,4), block 256. Block: 64 rows x 64 units x 4 gates. K=448.
__global__ __launch_bounds__(256) void kB_gates(
    const unsigned short* __restrict__ Ag, const unsigned short* __restrict__ Wg,
    const float* __restrict__ bsum, const float* __restrict__ c,
    float* __restrict__ h_new, float* __restrict__ c_new,
    unsigned short* __restrict__ Aout)
{
    __shared__ unsigned short As[64 * 32];
    __shared__ unsigned short Bs[256 * 32];
    int t = threadIdx.x;
    int wid = t >> 6, lane = t & 63;
    int cl = lane & 15, ks = lane >> 4;
    int b0 = blockIdx.x * 64;
    int u0 = blockIdx.y * 64;

    int arow = t >> 2;
    const unsigned short* aSrc = Ag + (size_t)(b0 + arow) * 448 + SW(arow, t & 3) * 8;
    unsigned short* aDst = As + wid * 512;
    const unsigned short* bSrc[4];
    unsigned short* bDst[4];
#pragma unroll
    for (int j = 0; j < 4; ++j) {
        int rl = (j * 256 + t) >> 2;
        int g = rl >> 6, u = rl & 63;
        bSrc[j] = Wg + (size_t)(g * 256 + u0 + u) * 448 + SW(rl, t & 3) * 8;
        bDst[j] = Bs + (j * 256 + wid * 64) * 8;
    }

    int aOff[4];
#pragma unroll
    for (int rf = 0; rf < 4; ++rf) {
        int mr = rf * 16 + cl;
        aOff[rf] = mr * 32 + SW(mr, ks) * 8;
    }
    int bOff[4];
#pragma unroll
    for (int g = 0; g < 4; ++g) {
        int br_ = g * 64 + wid * 16 + cl;
        bOff[g] = br_ * 32 + SW(br_, ks) * 8;
    }

    f32x4 acc[4][4] = {};  // [rf][g]
    for (int kc = 0; kc < 14; ++kc) {
        __syncthreads();
        GLL16(aSrc, aDst);
        GLL16(bSrc[0], bDst[0]); GLL16(bSrc[1], bDst[1]);
        GLL16(bSrc[2], bDst[2]); GLL16(bSrc[3], bDst[3]);
        aSrc += 32;
#pragma unroll
        for (int j = 0; j < 4; ++j) bSrc[j] += 32;
        __syncthreads();
        bf16x8 a[4], b[4];
#pragma unroll
        for (int rf = 0; rf < 4; ++rf) a[rf] = *(const bf16x8*)(As + aOff[rf]);
#pragma unroll
        for (int g = 0; g < 4; ++g) b[g] = *(const bf16x8*)(Bs + bOff[g]);
#pragma unroll
        for (int rf = 0; rf < 4; ++rf)
#pragma unroll
            for (int g = 0; g < 4; ++g)
                acc[rf][g] = MFMA16(a[rf], b[g], acc[rf][g]);
    }

    int unit = u0 + wid * 16 + cl;
    float bi = bsum[unit], bf_ = bsum[256 + unit];
    float bg = bsum[512 + unit], bo_ = bsum[768 + unit];
#pragma unroll
    for (int rf = 0; rf < 4; ++rf) {
#pragma unroll
        for (int r = 0; r < 4; ++r) {
            int row = b0 + rf * 16 + ks * 4 + r;
            float iv = sigf(acc[rf][0][r] + bi);
            float fv = sigf(acc[rf][1][r] + bf_);
            float gv = tanhf(acc[rf][2][r] + bg);
            float ov = sigf(acc[rf][3][r] + bo_);
            float cv = fv * c[(size_t)row * 256 + unit] + iv * gv;
            float hv = ov * tanhf(cv);
            c_new[(size_t)row * 256 + unit] = cv;
            h_new[(size_t)row * 256 + unit] = hv;
            Aout[(size_t)row * 320 + unit] = f2bf(hv);
        }
    }
}

// =============== kC: heads + out GEMM -> write_w/erase/addv/out ===============
// grid 256 (16 rows/block), block 256 (4 waves).
__global__ __launch_bounds__(256) void kC_heads_out(
    const unsigned short* __restrict__ Aout, const unsigned short* __restrict__ Wh_b,
    const unsigned short* __restrict__ Wo_b, const float* __restrict__ bh_b,
    const float* __restrict__ bo, float* __restrict__ write_w,
    float* __restrict__ erase, float* __restrict__ addv, float* __restrict__ outp)
{
    __shared__ unsigned short As[16 * 32];
    __shared__ unsigned short Bh[256 * 32];
    __shared__ unsigned short Bo[128 * 32];
    __shared__ float sc[16][256];

    int t = threadIdx.x;
    int wid = t >> 6, lane = t & 63;
    int cl = lane & 15, ks = lane >> 4;
    int b0 = blockIdx.x * 16;

    const unsigned short* aSrc = Aout + (size_t)(b0 + (lane >> 2)) * 320 + SW(lane >> 2, lane & 3) * 8;
    const unsigned short* bhSrc[4];
    unsigned short* bhDst[4];
#pragma unroll
    for (int j = 0; j < 4; ++j) {
        int rl = (j * 256 + t) >> 2;
        bhSrc[j] = Wh_b + (size_t)rl * 256 + SW(rl, t & 3) * 8;
        bhDst[j] = Bh + (j * 256 + wid * 64) * 8;
    }
    const unsigned short* boSrc[2];
    unsigned short* boDst[2];
#pragma unroll
    for (int j = 0; j < 2; ++j) {
        int rj = j * 64 + (t >> 2);
        boSrc[j] = Wo_b + (size_t)rj * 320 + SW(rj, t & 3) * 8;
        boDst[j] = Bo + j * 2048 + wid * 512;
    }

    int aOff = cl * 32 + SW(cl, ks) * 8;
    int bOffH[4], bOffO[2];
#pragma unroll
    for (int f = 0; f < 4; ++f) { int br_ = (wid * 4 + f) * 16 + cl; bOffH[f] = br_ * 32 + SW(br_, ks) * 8; }
#pragma unroll
    for (int f = 0; f < 2; ++f) { int br_ = (wid * 2 + f) * 16 + cl; bOffO[f] = br_ * 32 + SW(br_, ks) * 8; }

    f32x4 accH[4] = {};
    f32x4 accO[2] = {};
    for (int kc = 0; kc < 10; ++kc) {
        __syncthreads();
        if (t < 64) GLL16(aSrc, As);
        if (kc < 8) {
            GLL16(bhSrc[0], bhDst[0]); GLL16(bhSrc[1], bhDst[1]);
            GLL16(bhSrc[2], bhDst[2]); GLL16(bhSrc[3], bhDst[3]);
        }
        GLL16(boSrc[0], boDst[0]); GLL16(boSrc[1], boDst[1]);
        aSrc += 32;
#pragma unroll
        for (int j = 0; j < 4; ++j) bhSrc[j] += 32;
#pragma unroll
        for (int j = 0; j < 2; ++j) boSrc[j] += 32;
        __syncthreads();
        bf16x8 a = *(const bf16x8*)(As + aOff);
        if (kc < 8) {
#pragma unroll
            for (int f = 0; f < 4; ++f)
                accH[f] = MFMA16(a, *(const bf16x8*)(Bh + bOffH[f]), accH[f]);
        }
#pragma unroll
        for (int f = 0; f < 2; ++f)
            accO[f] = MFMA16(a, *(const bf16x8*)(Bo + bOffO[f]), accO[f]);
    }

    // head scores -> LDS; out -> global directly
#pragma unroll
    for (int f = 0; f < 4; ++f) {
        int col = (wid * 4 + f) * 16 + cl;
        float bb = bh_b[col];
#pragma unroll
        for (int r = 0; r < 4; ++r)
            sc[ks * 4 + r][col] = accH[f][r] + bb;
    }
#pragma unroll
    for (int f = 0; f < 2; ++f) {
        int col = (wid * 2 + f) * 16 + cl;
        float bb = bo[col];
#pragma unroll
        for (int r = 0; r < 4; ++r)
            outp[(size_t)(b0 + ks * 4 + r) * 128 + col] = accO[f][r] + bb;
    }
    __syncthreads();
    {   // softmax (write cols) + sigmoid/tanh (erase/add) -> global ws
        int row = t >> 4, l = t & 15;
        float v[8];
#pragma unroll
        for (int j = 0; j < 8; ++j) v[j] = sc[row][l + 16 * j];
        float m = v[0];
#pragma unroll
        for (int j = 1; j < 8; ++j) m = fmaxf(m, v[j]);
#pragma unroll
        for (int mk = 8; mk >= 1; mk >>= 1) m = fmaxf(m, __shfl_xor(m, mk));
        float s = 0.f;
#pragma unroll
        for (int j = 0; j < 8; ++j) { v[j] = __expf(v[j] - m); s += v[j]; }
#pragma unroll
        for (int mk = 8; mk >= 1; mk >>= 1) s += __shfl_xor(s, mk);
        float inv = 1.f / s;
        int row_g = b0 + row;
#pragma unroll
        for (int j = 0; j < 8; ++j)
            write_w[(size_t)row_g * 128 + l + 16 * j] = v[j] * inv;
#pragma unroll
        for (int j = 0; j < 4; ++j)
            erase[(size_t)row_g * 64 + l + 16 * j] = sigf(sc[row][128 + l + 16 * j]);
#pragma unroll
        for (int j = 0; j < 4; ++j)
            addv[(size_t)row_g * 64 + l + 16 * j] = tanhf(sc[row][192 + l + 16 * j]);
    }
}

// =============== k5: mem RMW stream (grid 4096, NT stores) ===============
__global__ __launch_bounds__(256) void k5_mem_update(
    const float* __restrict__ mem, const float* __restrict__ write_w,
    const float* __restrict__ erase, const float* __restrict__ addv,
    float* __restrict__ mem_new)
{
    int t = threadIdx.x; int b = blockIdx.x;
    int np = t >> 4, d0 = (t & 15) * 4;
    const f32x4* m4 = (const f32x4*)(mem + (size_t)b * 8192);
    f32x4* o4 = (f32x4*)(mem_new + (size_t)b * 8192);
    f32x4 e4 = *(const f32x4*)(erase + (size_t)b * 64 + d0);
    f32x4 a4 = *(const f32x4*)(addv + (size_t)b * 64 + d0);
#pragma unroll
    for (int j = 0; j < 8; ++j) {
        int n = np + 16 * j;
        float w = write_w[(size_t)b * 128 + n];
        f32x4 m = m4[t + 256 * j];
        f32x4 r;
        r[0] = m[0] * (1.f - w * e4[0]) + w * a4[0];
        r[1] = m[1] * (1.f - w * e4[1]) + w * a4[1];
        r[2] = m[2] * (1.f - w * e4[2]) + w * a4[2];
        r[3] = m[3] * (1.f - w * e4[3]) + w * a4[3];
        __builtin_nontemporal_store(r, &o4[t + 256 * j]);
    }
}

extern "C" void kernel_launch(void* const* d_in, const int* in_sizes, int n_in,
                              void* d_out, int out_size, void* d_ws, size_t ws_size,
                              hipStream_t stream)
{
    const float* x    = (const float*)d_in[0];
    const float* mem  = (const float*)d_in[1];
    const float* h    = (const float*)d_in[2];
    const float* c    = (const float*)d_in[3];
    const float* Wih  = (const float*)d_in[4];
    const float* Whh  = (const float*)d_in[5];
    const float* bih  = (const float*)d_in[6];
    const float* bhh  = (const float*)d_in[7];
    const float* Wr   = (const float*)d_in[8];
    const float* br   = (const float*)d_in[9];
    const float* Ww   = (const float*)d_in[10];
    const float* bw   = (const float*)d_in[11];
    const float* We   = (const float*)d_in[12];
    const float* be   = (const float*)d_in[13];
    const float* Wa   = (const float*)d_in[14];
    const float* ba   = (const float*)d_in[15];
    const float* Wo   = (const float*)d_in[16];
    const float* bo   = (const float*)d_in[17];

    float* out     = (float*)d_out;
    float* mem_new = out + 524288;
    float* h_new   = out + 34078720;
    float* c_new   = out + 35127296;

    float* ws      = (float*)d_ws;
    float* read_w  = ws;                       // 4096*128
    float* write_w = ws + 524288;              // 4096*128
    float* erase   = ws + 1048576;             // 4096*64
    float* addv    = ws + 1310720;             // 4096*64
    float* bsum    = ws + 1572864;             // 1024
    float* bh_b    = ws + 1573888;             // 256
    unsigned short* ub   = (unsigned short*)(ws + 1574144);
    unsigned short* Ag   = ub;                 // 4096*448 = 1835008
    unsigned short* Aout = ub + 1835008;       // 4096*320 = 1310720
    unsigned short* Wg   = ub + 3145728;       // 1024*448 = 458752
    unsigned short* Wh_b = ub + 3604480;       // 256*256  = 65536
    unsigned short* Wo_b = ub + 3670016;       // 128*320  = 40960

    kA_prep<<<256, 256, 0, stream>>>(Wih, Whh, bih, bhh, Wr, br, Ww, We, Wa, bw, be, ba,
                                     Wo, x, h, Wg, bsum, Wh_b, bh_b, Wo_b, Ag, read_w);
    k2_read_vec<<<4096, 256, 0, stream>>>(mem, read_w, Ag, Aout);
    kB_gates<<<dim3(64, 4), 256, 0, stream>>>(Ag, Wg, bsum, c, h_new, c_new, Aout);
    kC_heads_out<<<256, 256, 0, stream>>>(Aout, Wh_b, Wo_b, bh_b, bo,
                                          write_w, erase, addv, out);
    k5_mem_update<<<4096, 256, 0, stream>>>(mem, write_w, erase, addv, mem_new);
}

// Round 7
// 109.216 us; speedup vs baseline: 1.7959x; 1.0241x over previous
//
#include <hip/hip_runtime.h>
#include <math.h>

// Shapes: B=4096, N=128, D=64, H=256, O=128
// d_out (floats): out[B*128] | mem_new[B*128*64] | h_new[B*256] | c_new[B*256]
// ws: read_w f32[524288] | bsum f32[1024] | bh_b f32[256] | rvf f32[262144] |
//     bf16: Ag[4096][448]=[x|rv|h] | Wg[1024][448] | Wh_b[256][256] | Wo_b[128][320]

typedef __attribute__((ext_vector_type(8))) short bf16x8;
typedef __attribute__((ext_vector_type(4))) float f32x4;
typedef __attribute__((ext_vector_type(4))) unsigned short us4;

#define MFMA16(a, b, c) __builtin_amdgcn_mfma_f32_16x16x32_bf16(a, b, c, 0, 0, 0)
#define GLL16(gp, lp) __builtin_amdgcn_global_load_lds( \
    (const __attribute__((address_space(1))) void*)(gp), \
    (__attribute__((address_space(3))) void*)(lp), 16, 0, 0)
#define SW(row, s) ((s) ^ ((row) & 3))

__device__ __forceinline__ float sigf(float v) { return 1.f / (1.f + __expf(-v)); }

__device__ __forceinline__ unsigned short f2bf(float f) {
    unsigned u = __builtin_bit_cast(unsigned, f);
    u = (u + 0x7FFFu + ((u >> 16) & 1u)) >> 16;
    return (unsigned short)u;
}

// swizzled addr in a [4][320] bf16 LDS tile
__device__ __forceinline__ int swA(int r, int c) {
    return r * 320 + (c & ~31) + ((((c >> 3) & 3) ^ (r & 3)) << 3) + (c & 7);
}

// =============== kA: read-attn scores + softmax -> read_w ===============
// grid 256 (16 rows/block), block 256 (4 waves). K=256, f32->bf16 staged in-kernel.
__global__ __launch_bounds__(256) void kA_scores(
    const float* __restrict__ h, const float* __restrict__ Wr,
    const float* __restrict__ br, float* __restrict__ read_w)
{
    __shared__ unsigned short As[16 * 32];
    __shared__ unsigned short Bs[128 * 32];
    __shared__ float sc[16][128];

    int t = threadIdx.x;
    int wid = t >> 6, lane = t & 63;
    int cl = lane & 15, ks = lane >> 4;
    int b0 = blockIdx.x * 16;

    int aOff = cl * 32 + SW(cl, ks) * 8;
    int bOff[4];
#pragma unroll
    for (int f = 0; f < 4; ++f) {
        int br_ = (wid * 4 + f) * 16 + cl;
        bOff[f] = br_ * 32 + SW(br_, ks) * 8;
    }
    f32x4 acc[4] = {};
    for (int kc = 0; kc < 8; ++kc) {
        __syncthreads();
        {   // h tile: 16 rows x 32 k
            int row = t >> 4, k0 = (t & 15) * 2;
            float2 hv = *(const float2*)(h + (size_t)(b0 + row) * 256 + kc * 32 + k0);
            unsigned pk = (unsigned)f2bf(hv.x) | ((unsigned)f2bf(hv.y) << 16);
            *(unsigned*)(As + row * 32 + SW(row, k0 >> 3) * 8 + (k0 & 7)) = pk;
        }
        {   // Wr tile: 128 rows x 32 k
            int row = t >> 1, k0 = (t & 1) * 16;
            const float4* wp = (const float4*)(Wr + (size_t)row * 256 + kc * 32 + k0);
            float4 w0 = wp[0], w1 = wp[1], w2 = wp[2], w3 = wp[3];
            us4 p0 = { f2bf(w0.x), f2bf(w0.y), f2bf(w0.z), f2bf(w0.w) };
            us4 p1 = { f2bf(w1.x), f2bf(w1.y), f2bf(w1.z), f2bf(w1.w) };
            us4 p2 = { f2bf(w2.x), f2bf(w2.y), f2bf(w2.z), f2bf(w2.w) };
            us4 p3 = { f2bf(w3.x), f2bf(w3.y), f2bf(w3.z), f2bf(w3.w) };
            int g0 = k0 >> 3;
            unsigned short* basep = Bs + row * 32;
            *(us4*)(basep + SW(row, g0) * 8)         = p0;
            *(us4*)(basep + SW(row, g0) * 8 + 4)     = p1;
            *(us4*)(basep + SW(row, g0 + 1) * 8)     = p2;
            *(us4*)(basep + SW(row, g0 + 1) * 8 + 4) = p3;
        }
        __syncthreads();
        if (wid < 2) {
            bf16x8 a = *(const bf16x8*)(As + aOff);
#pragma unroll
            for (int f = 0; f < 4; ++f)
                acc[f] = MFMA16(a, *(const bf16x8*)(Bs + bOff[f]), acc[f]);
        }
    }
    if (wid < 2) {
#pragma unroll
        for (int f = 0; f < 4; ++f)
#pragma unroll
            for (int r = 0; r < 4; ++r)
                sc[ks * 4 + r][(wid * 4 + f) * 16 + cl] = acc[f][r];
    }
    __syncthreads();
    {
        int row = t >> 4, l = t & 15;
        float v[8];
#pragma unroll
        for (int j = 0; j < 8; ++j) v[j] = sc[row][l + 16 * j] + br[l + 16 * j];
        float m = v[0];
#pragma unroll
        for (int j = 1; j < 8; ++j) m = fmaxf(m, v[j]);
#pragma unroll
        for (int mk = 8; mk >= 1; mk >>= 1) m = fmaxf(m, __shfl_xor(m, mk));
        float s = 0.f;
#pragma unroll
        for (int j = 0; j < 8; ++j) { v[j] = __expf(v[j] - m); s += v[j]; }
#pragma unroll
        for (int mk = 8; mk >= 1; mk >>= 1) s += __shfl_xor(s, mk);
        float inv = 1.f / s;
#pragma unroll
        for (int j = 0; j < 8; ++j)
            read_w[(size_t)(b0 + row) * 128 + l + 16 * j] = v[j] * inv;
    }
}

// =============== k2: pack (striped, rides under HBM stream) + rv stream ===============
// grid 4096 (1 row/block), block 256.
__global__ __launch_bounds__(256) void k2_stream_pack(
    const float* __restrict__ mem, const float* __restrict__ read_w,
    const float* __restrict__ x, const float* __restrict__ h,
    const float* __restrict__ Wih, const float* __restrict__ Whh,
    const float* __restrict__ bih, const float* __restrict__ bhh,
    const float* __restrict__ Ww, const float* __restrict__ We,
    const float* __restrict__ Wa, const float* __restrict__ bw,
    const float* __restrict__ be, const float* __restrict__ ba,
    const float* __restrict__ Wo,
    unsigned short* __restrict__ Wg, unsigned short* __restrict__ Wh_b,
    unsigned short* __restrict__ Wo_b, float* __restrict__ bsum,
    float* __restrict__ bh_b, unsigned short* __restrict__ Ag,
    float* __restrict__ rvf)
{
    __shared__ float part[16][68];
    int t = threadIdx.x;
    int b = blockIdx.x;
    unsigned idx = b * 256 + t;     // 0 .. 1048575

    // ---- striped packs (each < 1 grid-stride) ----
    if (idx < 458752) {
        int r = idx / 448, cc = idx - r * 448;
        float v = (cc < 192) ? Wih[(size_t)r * 192 + cc] : Whh[(size_t)r * 256 + (cc - 192)];
        Wg[idx] = f2bf(v);
    }
    if (idx < 65536) {
        int r = idx >> 8, cc = idx & 255;
        float v = (r < 128) ? Ww[(size_t)r * 256 + cc]
                : (r < 192) ? We[(size_t)(r - 128) * 256 + cc]
                            : Wa[(size_t)(r - 192) * 256 + cc];
        Wh_b[idx] = f2bf(v);
    }
    if (idx < 40960) Wo_b[idx] = f2bf(Wo[idx]);
    if (idx < 1024)  bsum[idx] = bih[idx] + bhh[idx];
    if (idx < 256)
        bh_b[idx] = (idx < 128) ? bw[idx] : (idx < 192 ? be[idx - 128] : ba[idx - 192]);

    // ---- own-row x/h pack into Ag ----
    if (t < 96) {
        int j = t;
        float4 v = (j < 32) ? ((const float4*)(x + (size_t)b * 128))[j]
                            : ((const float4*)(h + (size_t)b * 256))[j - 32];
        us4 o = { f2bf(v.x), f2bf(v.y), f2bf(v.z), f2bf(v.w) };
        int col = (j < 32) ? j * 4 : 192 + (j - 32) * 4;
        *(us4*)(Ag + (size_t)b * 448 + col) = o;
    }

    // ---- rv = read_w . mem[b] stream ----
    int np = t >> 4, d4 = t & 15;
    const float4* m4 = (const float4*)(mem + (size_t)b * 8192);
    float4 acc = make_float4(0.f, 0.f, 0.f, 0.f);
#pragma unroll
    for (int j = 0; j < 8; ++j) {
        int n = np + 16 * j;
        float w = read_w[(size_t)b * 128 + n];
        float4 mv = m4[t + 256 * j];
        acc.x += w * mv.x; acc.y += w * mv.y; acc.z += w * mv.z; acc.w += w * mv.w;
    }
    part[np][d4 * 4 + 0] = acc.x; part[np][d4 * 4 + 1] = acc.y;
    part[np][d4 * 4 + 2] = acc.z; part[np][d4 * 4 + 3] = acc.w;
    __syncthreads();
    if (t < 64) {
        float s = 0.f;
#pragma unroll
        for (int q = 0; q < 16; ++q) s += part[q][t];
        Ag[(size_t)b * 448 + 128 + t] = f2bf(s);
        rvf[(size_t)b * 64 + t] = s;
    }
}

// =============== kB: gates GEMM [MFMA] + LSTM pointwise ===============
// grid (128,4) = 512 blocks (2/CU). Block: 32 rows x 64 units x 4 gates. K=448.
__global__ __launch_bounds__(256) void kB_gates(
    const unsigned short* __restrict__ Ag, const unsigned short* __restrict__ Wg,
    const float* __restrict__ bsum, const float* __restrict__ c,
    float* __restrict__ h_new, float* __restrict__ c_new)
{
    __shared__ unsigned short As[32 * 32];
    __shared__ unsigned short Bs[256 * 32];
    int t = threadIdx.x;
    int wid = t >> 6, lane = t & 63;
    int cl = lane & 15, ks = lane >> 4;
    int b0 = blockIdx.x * 32;
    int u0 = blockIdx.y * 64;

    int arow = (t >> 2) & 31;
    const unsigned short* aSrc = Ag + (size_t)(b0 + arow) * 448 + SW(arow, t & 3) * 8;
    unsigned short* aDst = As + wid * 512;   // waves 0,1 stage A
    const unsigned short* bSrc[4];
    unsigned short* bDst[4];
#pragma unroll
    for (int j = 0; j < 4; ++j) {
        int rl = (j * 256 + t) >> 2;        // 0..255
        int g = rl >> 6, u = rl & 63;
        bSrc[j] = Wg + (size_t)(g * 256 + u0 + u) * 448 + SW(rl, t & 3) * 8;
        bDst[j] = Bs + (j * 256 + wid * 64) * 8;
    }

    int aOff[2];
#pragma unroll
    for (int rf = 0; rf < 2; ++rf) {
        int mr = rf * 16 + cl;
        aOff[rf] = mr * 32 + SW(mr, ks) * 8;
    }
    int bOff[4];
#pragma unroll
    for (int g = 0; g < 4; ++g) {
        int br_ = g * 64 + wid * 16 + cl;
        bOff[g] = br_ * 32 + SW(br_, ks) * 8;
    }

    f32x4 acc[2][4] = {};  // [rf][g]
    for (int kc = 0; kc < 14; ++kc) {
        __syncthreads();
        if (wid < 2) GLL16(aSrc, aDst);
        GLL16(bSrc[0], bDst[0]); GLL16(bSrc[1], bDst[1]);
        GLL16(bSrc[2], bDst[2]); GLL16(bSrc[3], bDst[3]);
        aSrc += 32;
#pragma unroll
        for (int j = 0; j < 4; ++j) bSrc[j] += 32;
        __syncthreads();
        bf16x8 a[2], b[4];
#pragma unroll
        for (int rf = 0; rf < 2; ++rf) a[rf] = *(const bf16x8*)(As + aOff[rf]);
#pragma unroll
        for (int g = 0; g < 4; ++g) b[g] = *(const bf16x8*)(Bs + bOff[g]);
#pragma unroll
        for (int rf = 0; rf < 2; ++rf)
#pragma unroll
            for (int g = 0; g < 4; ++g)
                acc[rf][g] = MFMA16(a[rf], b[g], acc[rf][g]);
    }

    int unit = u0 + wid * 16 + cl;
    float bi = bsum[unit], bf_ = bsum[256 + unit];
    float bg = bsum[512 + unit], bo_ = bsum[768 + unit];
#pragma unroll
    for (int rf = 0; rf < 2; ++rf) {
#pragma unroll
        for (int r = 0; r < 4; ++r) {
            int row = b0 + rf * 16 + ks * 4 + r;
            float iv = sigf(acc[rf][0][r] + bi);
            float fv = sigf(acc[rf][1][r] + bf_);
            float gv = tanhf(acc[rf][2][r] + bg);
            float ov = sigf(acc[rf][3][r] + bo_);
            float cv = fv * c[(size_t)row * 256 + unit] + iv * gv;
            float hv = ov * tanhf(cv);
            c_new[(size_t)row * 256 + unit] = cv;
            h_new[(size_t)row * 256 + unit] = hv;
        }
    }
}

// =============== kC5: heads+out GEMM + softmax + mem RMW, fused ===============
// grid 1024 (4 rows/block, 4 blocks/CU), block 256 (4 waves).
__global__ __launch_bounds__(256) void kC5(
    const float* __restrict__ h_new, const float* __restrict__ rvf,
    const unsigned short* __restrict__ Wh_b, const unsigned short* __restrict__ Wo_b,
    const float* __restrict__ bh_b, const float* __restrict__ bo,
    const float* __restrict__ mem, float* __restrict__ outp,
    float* __restrict__ mem_new)
{
    __shared__ unsigned short As[4 * 320];   // K=320 fully resident, swizzled
    __shared__ unsigned short Bh[256 * 32];
    __shared__ unsigned short Bo[128 * 32];
    __shared__ float sc[4][384];
    __shared__ float wL[4][128];
    __shared__ __align__(16) float eL[4][64];
    __shared__ __align__(16) float aL[4][64];

    int t = threadIdx.x;
    int wid = t >> 6, lane = t & 63;
    int cl = lane & 15, ks = lane >> 4;
    int b0 = blockIdx.x * 4;

    // ---- stage A once: 4 rows x [h_new(256)|rv(64)] f32 -> bf16 ----
    for (int i = t; i < 4 * 320; i += 256) {
        int row = i / 320, col = i - row * 320;
        float v = (col < 256) ? h_new[(size_t)(b0 + row) * 256 + col]
                              : rvf[(size_t)(b0 + row) * 64 + (col - 256)];
        As[swA(row, col)] = f2bf(v);
    }

    const unsigned short* bhSrc[4];
    unsigned short* bhDst[4];
#pragma unroll
    for (int j = 0; j < 4; ++j) {
        int rl = (j * 256 + t) >> 2;
        bhSrc[j] = Wh_b + (size_t)rl * 256 + SW(rl, t & 3) * 8;
        bhDst[j] = Bh + (j * 256 + wid * 64) * 8;
    }
    const unsigned short* boSrc[2];
    unsigned short* boDst[2];
#pragma unroll
    for (int j = 0; j < 2; ++j) {
        int rj = j * 64 + (t >> 2);
        boSrc[j] = Wo_b + (size_t)rj * 320 + SW(rj, t & 3) * 8;
        boDst[j] = Bo + j * 2048 + wid * 512;
    }

    // wave wid owns heads frags (wid+4j), j=0..3; out frags (wid+4j), j=0..1
    int bOffH[4], bOffO[2];
#pragma unroll
    for (int j = 0; j < 4; ++j) { int br_ = (wid + 4 * j) * 16 + cl; bOffH[j] = br_ * 32 + SW(br_, ks) * 8; }
#pragma unroll
    for (int j = 0; j < 2; ++j) { int br_ = (wid + 4 * j) * 16 + cl; bOffO[j] = br_ * 32 + SW(br_, ks) * 8; }

    f32x4 accH[4] = {};
    f32x4 accO[2] = {};
    for (int kc = 0; kc < 10; ++kc) {
        __syncthreads();
        if (kc < 8) {
            GLL16(bhSrc[0], bhDst[0]); GLL16(bhSrc[1], bhDst[1]);
            GLL16(bhSrc[2], bhDst[2]); GLL16(bhSrc[3], bhDst[3]);
#pragma unroll
            for (int j = 0; j < 4; ++j) bhSrc[j] += 32;
        }
        GLL16(boSrc[0], boDst[0]); GLL16(boSrc[1], boDst[1]);
#pragma unroll
        for (int j = 0; j < 2; ++j) boSrc[j] += 32;
        __syncthreads();
        bf16x8 a = *(const bf16x8*)(As + swA(cl & 3, kc * 32 + ks * 8));
        if (kc < 8) {
#pragma unroll
            for (int j = 0; j < 4; ++j)
                accH[j] = MFMA16(a, *(const bf16x8*)(Bh + bOffH[j]), accH[j]);
        }
#pragma unroll
        for (int j = 0; j < 2; ++j)
            accO[j] = MFMA16(a, *(const bf16x8*)(Bo + bOffO[j]), accO[j]);
    }

    // only lanes ks==0 hold real rows 0..3 (rows 4..15 are duplicates of A-rows)
    if (ks == 0) {
#pragma unroll
        for (int j = 0; j < 4; ++j) {
            int col = (wid + 4 * j) * 16 + cl;
            float bb = bh_b[col];
#pragma unroll
            for (int r = 0; r < 4; ++r) sc[r][col] = accH[j][r] + bb;
        }
#pragma unroll
        for (int j = 0; j < 2; ++j) {
            int ocol = (wid + 4 * j) * 16 + cl;
            float bb = bo[ocol];
#pragma unroll
            for (int r = 0; r < 4; ++r)
                outp[(size_t)(b0 + r) * 128 + ocol] = accO[j][r] + bb;
        }
    }
    __syncthreads();

    if (t < 64) {   // softmax (write cols) + sigmoid/tanh (erase/add), 4 rows
        int row = t >> 4, l = t & 15;
        float v[8];
#pragma unroll
        for (int j = 0; j < 8; ++j) v[j] = sc[row][l + 16 * j];
        float m = v[0];
#pragma unroll
        for (int j = 1; j < 8; ++j) m = fmaxf(m, v[j]);
#pragma unroll
        for (int mk = 8; mk >= 1; mk >>= 1) m = fmaxf(m, __shfl_xor(m, mk));
        float s = 0.f;
#pragma unroll
        for (int j = 0; j < 8; ++j) { v[j] = __expf(v[j] - m); s += v[j]; }
#pragma unroll
        for (int mk = 8; mk >= 1; mk >>= 1) s += __shfl_xor(s, mk);
        float inv = 1.f / s;
#pragma unroll
        for (int j = 0; j < 8; ++j) wL[row][l + 16 * j] = v[j] * inv;
#pragma unroll
        for (int j = 0; j < 4; ++j) eL[row][l + 16 * j] = sigf(sc[row][128 + l + 16 * j]);
#pragma unroll
        for (int j = 0; j < 4; ++j) aL[row][l + 16 * j] = tanhf(sc[row][192 + l + 16 * j]);
    }
    __syncthreads();

    // ---- mem RMW stream: wave wid handles row wid ----
    {
        int r = wid;
        const f32x4* m4 = (const f32x4*)(mem + (size_t)(b0 + r) * 8192);
        f32x4* o4 = (f32x4*)(mem_new + (size_t)(b0 + r) * 8192);
        f32x4 e4 = *(const f32x4*)&eL[r][(lane & 15) * 4];
        f32x4 a4 = *(const f32x4*)&aL[r][(lane & 15) * 4];
        f32x4 one = {1.f, 1.f, 1.f, 1.f};
#pragma unroll
        for (int j = 0; j < 32; ++j) {
            int idx = j * 64 + lane;
            float w = wL[r][j * 4 + (lane >> 4)];
            f32x4 m = m4[idx];
            f32x4 res = m * (one - e4 * w) + a4 * w;
            __builtin_nontemporal_store(res, &o4[idx]);
        }
    }
}

extern "C" void kernel_launch(void* const* d_in, const int* in_sizes, int n_in,
                              void* d_out, int out_size, void* d_ws, size_t ws_size,
                              hipStream_t stream)
{
    const float* x    = (const float*)d_in[0];
    const float* mem  = (const float*)d_in[1];
    const float* h    = (const float*)d_in[2];
    const float* c    = (const float*)d_in[3];
    const float* Wih  = (const float*)d_in[4];
    const float* Whh  = (const float*)d_in[5];
    const float* bih  = (const float*)d_in[6];
    const float* bhh  = (const float*)d_in[7];
    const float* Wr   = (const float*)d_in[8];
    const float* br   = (const float*)d_in[9];
    const float* Ww   = (const float*)d_in[10];
    const float* bw   = (const float*)d_in[11];
    const float* We   = (const float*)d_in[12];
    const float* be   = (const float*)d_in[13];
    const float* Wa   = (const float*)d_in[14];
    const float* ba   = (const float*)d_in[15];
    const float* Wo   = (const float*)d_in[16];
    const float* bo   = (const float*)d_in[17];

    float* out     = (float*)d_out;
    float* mem_new = out + 524288;
    float* h_new   = out + 34078720;
    float* c_new   = out + 35127296;

    float* ws      = (float*)d_ws;
    float* read_w  = ws;                       // 4096*128 = 524288
    float* bsum    = ws + 524288;              // 1024
    float* bh_b    = ws + 525312;              // 256
    float* rvf     = ws + 525568;              // 4096*64 = 262144
    unsigned short* ub   = (unsigned short*)(ws + 787712);
    unsigned short* Ag   = ub;                 // 4096*448 = 1835008
    unsigned short* Wg   = ub + 1835008;       // 1024*448 = 458752
    unsigned short* Wh_b = ub + 2293760;       // 256*256  = 65536
    unsigned short* Wo_b = ub + 2359296;       // 128*320  = 40960

    kA_scores<<<256, 256, 0, stream>>>(h, Wr, br, read_w);
    k2_stream_pack<<<4096, 256, 0, stream>>>(mem, read_w, x, h, Wih, Whh, bih, bhh,
                                             Ww, We, Wa, bw, be, ba, Wo,
                                             Wg, Wh_b, Wo_b, bsum, bh_b, Ag, rvf);
    kB_gates<<<dim3(128, 4), 256, 0, stream>>>(Ag, Wg, bsum, c, h_new, c_new);
    kC5<<<1024, 256, 0, stream>>>(h_new, rvf, Wh_b, Wo_b, bh_b, bo, mem, out, mem_new);
}